// Round 21
// baseline (698.936 us; speedup 1.0000x reference)
//
#include <hip/hip_runtime.h>
#include <hip/hip_bf16.h>
#include <hip/hip_fp16.h>

#define HID 64
#define HEADS 4
#define GCNT 64
#define F_IN 16
#define NEG 0.2f
#define NBUCK 256
#define BSLOT 6144
#define SCHUNK 2048

typedef _Float16 f16x8 __attribute__((ext_vector_type(8)));
typedef float f32x4 __attribute__((ext_vector_type(4)));

__device__ __forceinline__ unsigned pack_h2(float a, float b) {
  __half2 h = __floats2half2_rn(a, b);
  union { __half2 h; unsigned u; } c;
  c.h = h;
  return c.u;
}
__device__ __forceinline__ __half2 uas_h2(unsigned u) {
  union { unsigned u; __half2 h; } c;
  c.u = u;
  return c.h;
}
__device__ __forceinline__ unsigned h2_as_u(__half2 h) {
  union { __half2 h; unsigned u; } c;
  c.h = h;
  return c.u;
}
__device__ __forceinline__ __half2 xor16_add(__half2 v) {
  unsigned u = (unsigned)__shfl_xor((int)h2_as_u(v), 16, 64);
  return __hadd2(v, uas_h2(u));
}

// ---------------- pre: zero cursors/hist + fold layer-0 attn through Win ----------------
__global__ __launch_bounds__(256) void k_pre(
    const float* __restrict__ W0, const float* __restrict__ asrc,
    const float* __restrict__ adst, const float* __restrict__ Win,
    const float* __restrict__ bin, int* __restrict__ bcur,
    int* __restrict__ ghist, float* __restrict__ vb, float* __restrict__ c8) {
  int t = threadIdx.x;
  if (blockIdx.x == 0) {
    bcur[t] = 0;
    ghist[t] = 0;
    return;
  }
  __shared__ float vaL[512];
#pragma unroll
  for (int it = 0; it < 2; ++it) {
    int idx = t + it * 256;
    int q = idx >> 6, j = idx & 63;
    const float* a = (q < 4) ? asrc : adst;
    int h = q & 3;
    float s = 0.f;
    for (int c = 0; c < 64; ++c) s += a[h * 64 + c] * W0[(h * 64 + c) * 64 + j];
    vaL[idx] = s;
  }
  __syncthreads();
  if (t < 128) {
    int q = t >> 4, k = t & 15;
    float s = 0.f;
    for (int j = 0; j < 64; ++j) s += vaL[q * 64 + j] * Win[j * F_IN + k];
    vb[t] = s;
  } else if (t < 136) {
    int q = t - 128;
    float s = 0.f;
    for (int j = 0; j < 64; ++j) s += vaL[q * 64 + j] * bin[j];
    c8[q] = s;
  }
}

// ---------------- CSR pass 1: bin edges by dst>>8 into fixed bucket regions ----------------
__global__ __launch_bounds__(256) void k_bucket(
    const int* __restrict__ ei, int* __restrict__ bcur,
    unsigned* __restrict__ tmp, int E, int N) {
  __shared__ int hist[NBUCK];
  __shared__ int base[NBUCK];
  int t = threadIdx.x;
  int start = blockIdx.x * SCHUNK;
  int end = min(start + SCHUNK, E + N);
  hist[t] = 0;
  __syncthreads();
  unsigned val[8];
  int rank[8];
  bool ok[8];
#pragma unroll
  for (int k = 0; k < 8; ++k) {
    int i = start + t + k * 256;
    ok[k] = i < end;
    if (ok[k]) {
      int s, d;
      if (i < E) {
        s = ei[i];
        d = ei[E + i];
      } else {
        s = d = i - E;
      }
      val[k] = ((unsigned)d << 16) | (unsigned)s;
      rank[k] = atomicAdd(&hist[d >> 8], 1);
    }
  }
  __syncthreads();
  int h = hist[t];
  base[t] = h ? atomicAdd(&bcur[t], h) : 0;
  __syncthreads();
#pragma unroll
  for (int k = 0; k < 8; ++k) {
    if (ok[k]) {
      int bk = (int)(val[k] >> 24);
      int idx = base[bk] + rank[k];
      if (idx < BSLOT) tmp[(size_t)bk * BSLOT + idx] = val[k];
    }
  }
}

// ---------------- CSR pass 2: per-bucket counting sort -> rowptr + col (+degree hist) ----------------
__global__ __launch_bounds__(256) void k_bsort(
    const unsigned* __restrict__ tmp, const int* __restrict__ bcur,
    int* __restrict__ rowptr, int* __restrict__ col, int* __restrict__ ghist, int N) {
  __shared__ int s[NBUCK];
  __shared__ int hist[NBUCK];
  __shared__ int pref[NBUCK];
  int b = blockIdx.x, t = threadIdx.x;
  int c = min(bcur[t], BSLOT);
  s[t] = c;
  __syncthreads();
  for (int o = 1; o < 256; o <<= 1) {
    int x = (t >= o) ? s[t - o] : 0;
    __syncthreads();
    s[t] += x;
    __syncthreads();
  }
  int base = (b == 0) ? 0 : s[b - 1];
  int total = s[255];
  int cntb = min(bcur[b], BSLOT);
  hist[t] = 0;
  __syncthreads();
  for (int j = t; j < cntb; j += 256)
    atomicAdd(&hist[(tmp[(size_t)b * BSLOT + j] >> 16) & 255], 1);
  __syncthreads();
  int v = hist[t];
  int node = b * 256 + t;
  if (node < N) atomicAdd(&ghist[min(v, 255)], 1);   // degree histogram
  pref[t] = v;
  __syncthreads();
  for (int o = 1; o < 256; o <<= 1) {
    int x = (t >= o) ? pref[t - o] : 0;
    __syncthreads();
    pref[t] += x;
    __syncthreads();
  }
  pref[t] -= v;
  __syncthreads();
  if (node < N) rowptr[node] = base + pref[t];
  if (b == 255 && t == 255) rowptr[N] = total;
  hist[t] = 0;
  __syncthreads();
  for (int j = t; j < cntb; j += 256) {
    unsigned e = tmp[(size_t)b * BSLOT + j];
    int d8 = (int)((e >> 16) & 255);
    int r = atomicAdd(&hist[d8], 1);
    col[base + pref[d8] + r] = (int)(e & 0xffffu);
  }
}

// ---------------- degree-sort: scan hist -> cursors; scatter nodes by degree ----------------
__global__ __launch_bounds__(256) void k_dscan(const int* __restrict__ ghist,
                                               int* __restrict__ dcur) {
  __shared__ int s[256];
  int t = threadIdx.x;
  int v = ghist[t];
  s[t] = v;
  __syncthreads();
  for (int o = 1; o < 256; o <<= 1) {
    int x = (t >= o) ? s[t - o] : 0;
    __syncthreads();
    s[t] += x;
    __syncthreads();
  }
  dcur[t] = s[t] - v;
}

__global__ __launch_bounds__(256) void k_dperm(const int* __restrict__ rowptr,
                                               int* __restrict__ dcur,
                                               int* __restrict__ perm, int N) {
  int n = blockIdx.x * 256 + threadIdx.x;
  if (n >= N) return;
  int deg = rowptr[n + 1] - rowptr[n];
  int pos = atomicAdd(&dcur[min(deg, 255)], 1);
  perm[pos] = n;
}

// ---------------- init: weight prep + sums zero + inproj + folded layer-0 attn ----------------
__global__ void k_init(const float* __restrict__ x, const float* __restrict__ Win,
                       const float* __restrict__ bin,
                       const float* __restrict__ W0, const float* __restrict__ W1,
                       const float* __restrict__ W2,
                       __half* __restrict__ Wh3, __half* __restrict__ Wcat3,
                       float* __restrict__ sums, const float* __restrict__ vb,
                       const float* __restrict__ c8,
                       float* __restrict__ as_, float* __restrict__ ad_,
                       __half* __restrict__ hh, int N) {
  int b = blockIdx.x, t = threadIdx.x;
  if (b < 384) {
    int i = b * 256 + t;
    if (i < 49152) {
      const float* W = (i < 16384) ? W0 : (i < 32768) ? W1 : W2;
      Wh3[i] = __float2half(W[i & 16383]);
    } else {
      int j = i - 49152;
      int l = j >> 14;
      int r = j & 16383;
      int c = r >> 8;
      int k256 = r & 255;
      int h = k256 & 3, kk = k256 >> 2;
      const float* W = (l == 0) ? W0 : (l == 1) ? W1 : W2;
      Wcat3[j] = __float2half(0.25f * W[(h * 64 + c) * 64 + kk]);
    }
    return;
  }
  if (b < 401) {
    int i = (b - 384) * 256 + t;
    if (i < GCNT * HID + GCNT) sums[i] = 0.f;
    return;
  }
  int i = (b - 401) * 256 + t;
  if (i >= N * HID) return;
  int n = i >> 6, j = i & 63;
  const float* xr = x + (size_t)n * F_IN;
  const float* wr = Win + j * F_IN;
  float xv[F_IN];
  float acc = bin[j];
#pragma unroll
  for (int k = 0; k < F_IN; ++k) {
    xv[k] = xr[k];
    acc = fmaf(xv[k], wr[k], acc);
  }
  hh[i] = __float2half(acc);
  if (j < 8) {
    const float* vbq = vb + j * 16;
    float s = c8[j];
#pragma unroll
    for (int k = 0; k < F_IN; ++k) s = fmaf(xv[k], vbq[k], s);
    if (j < 4) as_[(size_t)n * 4 + j] = s;
    else ad_[(size_t)n * 4 + (j - 4)] = s;
  }
}

// ---------------- single-node helper (any deg): writes one M row to LDS ----------------
__device__ __forceinline__ void gat_one_node(
    int node, int lane, const __half* __restrict__ h, const float* __restrict__ as_,
    const float* __restrict__ ad_, const int* __restrict__ rowptr,
    const int* __restrict__ col, __half* __restrict__ Mrow) {
  int r0 = rowptr[node];
  int deg = rowptr[node + 1] - r0;
  float4 adv = *(const float4*)(ad_ + (size_t)node * 4);

  if (deg <= 64) {
    int off = 0;
    float x0 = 0.f, x1 = 0.f, x2 = 0.f, x3 = 0.f;
    if (lane < deg) {
      int s = col[r0 + lane];
      off = s << 6;
      float4 av = *(const float4*)(as_ + (size_t)s * 4);
      float e0 = av.x + adv.x; e0 = (e0 > 0.f) ? e0 : NEG * e0;
      float e1 = av.y + adv.y; e1 = (e1 > 0.f) ? e1 : NEG * e1;
      float e2 = av.z + adv.z; e2 = (e2 > 0.f) ? e2 : NEG * e2;
      float e3 = av.w + adv.w; e3 = (e3 > 0.f) ? e3 : NEG * e3;
      x0 = __expf(fminf(e0, 60.f));
      x1 = __expf(fminf(e1, 60.f));
      x2 = __expf(fminf(e2, 60.f));
      x3 = __expf(fminf(e3, 60.f));
    }
    float s0 = x0, s1 = x1, s2 = x2, s3 = x3;
#pragma unroll
    for (int o = 32; o; o >>= 1) {
      s0 += __shfl_xor(s0, o, 64);
      s1 += __shfl_xor(s1, o, 64);
      s2 += __shfl_xor(s2, o, 64);
      s3 += __shfl_xor(s3, o, 64);
    }
    unsigned w01 = pack_h2(x0 / (s0 + 1e-16f), x1 / (s1 + 1e-16f));
    unsigned w23 = pack_h2(x2 / (s2 + 1e-16f), x3 / (s3 + 1e-16f));
    __half2 acc01 = __floats2half2_rn(0.f, 0.f);
    __half2 acc23 = acc01;
#pragma unroll 4
    for (int j = 0; j < deg; ++j) {
      int oj = __builtin_amdgcn_readlane(off, j) + lane;
      unsigned W01 = __builtin_amdgcn_readlane(w01, j);
      unsigned W23 = __builtin_amdgcn_readlane(w23, j);
      __half2 hv = __half2half2(h[oj]);
      acc01 = __hfma2(hv, uas_h2(W01), acc01);
      acc23 = __hfma2(hv, uas_h2(W23), acc23);
    }
    *(__half2*)&Mrow[lane * 4] = acc01;
    *(__half2*)&Mrow[lane * 4 + 2] = acc23;
    return;
  }
  float m0 = -1e30f, m1 = -1e30f, m2 = -1e30f, m3 = -1e30f;
  for (int j = lane; j < deg; j += 64) {
    int s = col[r0 + j];
    float4 av = *(const float4*)(as_ + (size_t)s * 4);
    float e0 = av.x + adv.x; e0 = (e0 > 0.f) ? e0 : NEG * e0; m0 = fmaxf(m0, e0);
    float e1 = av.y + adv.y; e1 = (e1 > 0.f) ? e1 : NEG * e1; m1 = fmaxf(m1, e1);
    float e2 = av.z + adv.z; e2 = (e2 > 0.f) ? e2 : NEG * e2; m2 = fmaxf(m2, e2);
    float e3 = av.w + adv.w; e3 = (e3 > 0.f) ? e3 : NEG * e3; m3 = fmaxf(m3, e3);
  }
#pragma unroll
  for (int o = 32; o; o >>= 1) {
    m0 = fmaxf(m0, __shfl_xor(m0, o, 64));
    m1 = fmaxf(m1, __shfl_xor(m1, o, 64));
    m2 = fmaxf(m2, __shfl_xor(m2, o, 64));
    m3 = fmaxf(m3, __shfl_xor(m3, o, 64));
  }
  float s0 = 0.f, s1 = 0.f, s2 = 0.f, s3 = 0.f;
  for (int j = lane; j < deg; j += 64) {
    int s = col[r0 + j];
    float4 av = *(const float4*)(as_ + (size_t)s * 4);
    float e0 = av.x + adv.x; e0 = (e0 > 0.f) ? e0 : NEG * e0; s0 += __expf(e0 - m0);
    float e1 = av.y + adv.y; e1 = (e1 > 0.f) ? e1 : NEG * e1; s1 += __expf(e1 - m1);
    float e2 = av.z + adv.z; e2 = (e2 > 0.f) ? e2 : NEG * e2; s2 += __expf(e2 - m2);
    float e3 = av.w + adv.w; e3 = (e3 > 0.f) ? e3 : NEG * e3; s3 += __expf(e3 - m3);
  }
#pragma unroll
  for (int o = 32; o; o >>= 1) {
    s0 += __shfl_xor(s0, o, 64);
    s1 += __shfl_xor(s1, o, 64);
    s2 += __shfl_xor(s2, o, 64);
    s3 += __shfl_xor(s3, o, 64);
  }
  float i0 = 1.f / (s0 + 1e-16f), i1 = 1.f / (s1 + 1e-16f);
  float i2 = 1.f / (s2 + 1e-16f), i3 = 1.f / (s3 + 1e-16f);
  float a0 = 0.f, a1 = 0.f, a2 = 0.f, a3 = 0.f;
  for (int j = 0; j < deg; ++j) {
    int s = col[r0 + j];
    float4 av = *(const float4*)(as_ + (size_t)s * 4);
    float e0 = av.x + adv.x; e0 = (e0 > 0.f) ? e0 : NEG * e0;
    float e1 = av.y + adv.y; e1 = (e1 > 0.f) ? e1 : NEG * e1;
    float e2 = av.z + adv.z; e2 = (e2 > 0.f) ? e2 : NEG * e2;
    float e3 = av.w + adv.w; e3 = (e3 > 0.f) ? e3 : NEG * e3;
    float hv = __half2float(h[(s << 6) + lane]);
    a0 = fmaf(__expf(e0 - m0) * i0, hv, a0);
    a1 = fmaf(__expf(e1 - m1) * i1, hv, a1);
    a2 = fmaf(__expf(e2 - m2) * i2, hv, a2);
    a3 = fmaf(__expf(e3 - m3) * i3, hv, a3);
  }
  *(__half2*)&Mrow[lane * 4] = __floats2half2_rn(a0, a1);
  *(__half2*)&Mrow[lane * 4 + 2] = __floats2half2_rn(a2, a3);
}

// ---------------- one pair (serial path; handles slow cases); slots are perm indices ----------------
__device__ __forceinline__ void gat_pair(
    int pr, int lane, int half, int l5, int N, const int* __restrict__ perm,
    const __half* __restrict__ h, const float* __restrict__ as_,
    const float* __restrict__ ad_, const int* __restrict__ rowptr,
    const int* __restrict__ col, __half* __restrict__ Mt) {
  int s0i = pr * 2;
  int s1i = min(s0i + 1, N - 1);
  int myslot = half ? s1i : s0i;
  int mynode = perm[myslot];
  int r0 = rowptr[mynode];
  int dg = rowptr[mynode + 1] - r0;
  int dgA = __builtin_amdgcn_readlane(dg, 0);
  int dgB = __builtin_amdgcn_readlane(dg, 32);

  if (dgA <= 32 && dgB <= 32) {
    float4 adv = *(const float4*)(ad_ + (size_t)mynode * 4);
    int off = 0;
    float x0 = 0.f, x1 = 0.f, x2 = 0.f, x3 = 0.f;
    if (l5 < dg) {
      int s = col[r0 + l5];
      off = s << 6;
      float4 av = *(const float4*)(as_ + (size_t)s * 4);
      float e0 = av.x + adv.x; e0 = (e0 > 0.f) ? e0 : NEG * e0;
      float e1 = av.y + adv.y; e1 = (e1 > 0.f) ? e1 : NEG * e1;
      float e2 = av.z + adv.z; e2 = (e2 > 0.f) ? e2 : NEG * e2;
      float e3 = av.w + adv.w; e3 = (e3 > 0.f) ? e3 : NEG * e3;
      x0 = __expf(fminf(e0, 60.f));
      x1 = __expf(fminf(e1, 60.f));
      x2 = __expf(fminf(e2, 60.f));
      x3 = __expf(fminf(e3, 60.f));
    }
    float s0 = x0, s1 = x1, s2 = x2, s3 = x3;
#pragma unroll
    for (int o = 16; o; o >>= 1) {
      s0 += __shfl_xor(s0, o, 64);
      s1 += __shfl_xor(s1, o, 64);
      s2 += __shfl_xor(s2, o, 64);
      s3 += __shfl_xor(s3, o, 64);
    }
    unsigned w01 = pack_h2(x0 / (s0 + 1e-16f), x1 / (s1 + 1e-16f));
    unsigned w23 = pack_h2(x2 / (s2 + 1e-16f), x3 / (s3 + 1e-16f));

    int g = l5 >> 4, li = l5 & 15;
    const uint2* h4p = (const uint2*)h;
    __half2 z = __floats2half2_rn(0.f, 0.f);
    __half2 a0_01 = z, a0_23 = z, a1_01 = z, a1_23 = z;
    __half2 a2_01 = z, a2_23 = z, a3_01 = z, a3_23 = z;
    int mdeg = max(dgA, dgB);
    int baddr = half << 7;
#pragma unroll 2
    for (int j = 0; j < mdeg; j += 2) {
      int addr = baddr + (j + g) * 4;
      int oj = __builtin_amdgcn_ds_bpermute(addr, off);
      unsigned W01 = (unsigned)__builtin_amdgcn_ds_bpermute(addr, (int)w01);
      unsigned W23 = (unsigned)__builtin_amdgcn_ds_bpermute(addr, (int)w23);
      uint2 hv = h4p[(oj >> 2) + li];
      __half2 ha = uas_h2(hv.x), hb = uas_h2(hv.y);
      __half2 wA = uas_h2(W01), wB = uas_h2(W23);
      __half2 c0 = __low2half2(ha), c1 = __high2half2(ha);
      __half2 c2 = __low2half2(hb), c3 = __high2half2(hb);
      a0_01 = __hfma2(c0, wA, a0_01); a0_23 = __hfma2(c0, wB, a0_23);
      a1_01 = __hfma2(c1, wA, a1_01); a1_23 = __hfma2(c1, wB, a1_23);
      a2_01 = __hfma2(c2, wA, a2_01); a2_23 = __hfma2(c2, wB, a2_23);
      a3_01 = __hfma2(c3, wA, a3_01); a3_23 = __hfma2(c3, wB, a3_23);
    }
    a0_01 = xor16_add(a0_01); a0_23 = xor16_add(a0_23);
    a1_01 = xor16_add(a1_01); a1_23 = xor16_add(a1_23);
    a2_01 = xor16_add(a2_01); a2_23 = xor16_add(a2_23);
    a3_01 = xor16_add(a3_01); a3_23 = xor16_add(a3_23);
    if (g == 0) {
      __half* row = &Mt[(myslot & 15) * 264 + li * 16];
      uint4 st1, st2;
      st1.x = h2_as_u(a0_01); st1.y = h2_as_u(a0_23);
      st1.z = h2_as_u(a1_01); st1.w = h2_as_u(a1_23);
      st2.x = h2_as_u(a2_01); st2.y = h2_as_u(a2_23);
      st2.z = h2_as_u(a3_01); st2.w = h2_as_u(a3_23);
      *(uint4*)&row[0] = st1;
      *(uint4*)&row[8] = st2;
    }
  } else {
    gat_one_node(perm[s0i], lane, h, as_, ad_, rowptr, col, &Mt[(s0i & 15) * 264]);
    if (s1i != s0i) gat_one_node(perm[s1i], lane, h, as_, ad_, rowptr, col, &Mt[(s1i & 15) * 264]);
  }
}

// ---------------- fused GAT layer (degree-sorted tiles via perm) ----------------
template <bool FIN>
__global__ __launch_bounds__(256) void k_gatf(
    const __half* __restrict__ h, const float* __restrict__ as_,
    const float* __restrict__ ad_, const int* __restrict__ rowptr,
    const int* __restrict__ col, const int* __restrict__ perm,
    const __half* __restrict__ Wcat,
    const float* __restrict__ bg, const __half* __restrict__ Wn,
    const float* __restrict__ asrc, const float* __restrict__ adst,
    __half* __restrict__ hout, float* __restrict__ nas, float* __restrict__ nad,
    int N) {
  __shared__ __half Mt[16 * 264];
  __shared__ __half O[16 * 72];
  int tid = threadIdx.x;
  int lane = tid & 63, wv = tid >> 6;
  int tile = blockIdx.x;
  int half = lane >> 5, l5 = lane & 31;
  int npairs = (N + 1) >> 1;

  int pr0 = tile * 8 + wv * 2;
  int pr1 = pr0 + 1;
  bool has0 = pr0 < npairs, has1 = pr1 < npairs;
  if (has0 && has1) {
    int slotA = min(pr0 * 2 + half, N - 1);
    int slotB = min(pr1 * 2 + half, N - 1);
    int my0 = perm[slotA];
    int my1 = perm[slotB];
    int r0a = rowptr[my0];
    int dga = rowptr[my0 + 1] - r0a;
    int r0b = rowptr[my1];
    int dgb = rowptr[my1 + 1] - r0b;
    int dA0 = __builtin_amdgcn_readlane(dga, 0);
    int dB0 = __builtin_amdgcn_readlane(dga, 32);
    int dA1 = __builtin_amdgcn_readlane(dgb, 0);
    int dB1 = __builtin_amdgcn_readlane(dgb, 32);

    if (dA0 <= 32 && dB0 <= 32 && dA1 <= 32 && dB1 <= 32) {
      float4 adva = *(const float4*)(ad_ + (size_t)my0 * 4);
      float4 advb = *(const float4*)(ad_ + (size_t)my1 * 4);
      int offa = 0, offb = 0;
      float xa0 = 0.f, xa1 = 0.f, xa2 = 0.f, xa3 = 0.f;
      float xb0 = 0.f, xb1 = 0.f, xb2 = 0.f, xb3 = 0.f;
      if (l5 < dga) {
        int s = col[r0a + l5];
        offa = s << 6;
        float4 av = *(const float4*)(as_ + (size_t)s * 4);
        float e0 = av.x + adva.x; e0 = (e0 > 0.f) ? e0 : NEG * e0;
        float e1 = av.y + adva.y; e1 = (e1 > 0.f) ? e1 : NEG * e1;
        float e2 = av.z + adva.z; e2 = (e2 > 0.f) ? e2 : NEG * e2;
        float e3 = av.w + adva.w; e3 = (e3 > 0.f) ? e3 : NEG * e3;
        xa0 = __expf(fminf(e0, 60.f));
        xa1 = __expf(fminf(e1, 60.f));
        xa2 = __expf(fminf(e2, 60.f));
        xa3 = __expf(fminf(e3, 60.f));
      }
      if (l5 < dgb) {
        int s = col[r0b + l5];
        offb = s << 6;
        float4 av = *(const float4*)(as_ + (size_t)s * 4);
        float e0 = av.x + advb.x; e0 = (e0 > 0.f) ? e0 : NEG * e0;
        float e1 = av.y + advb.y; e1 = (e1 > 0.f) ? e1 : NEG * e1;
        float e2 = av.z + advb.z; e2 = (e2 > 0.f) ? e2 : NEG * e2;
        float e3 = av.w + advb.w; e3 = (e3 > 0.f) ? e3 : NEG * e3;
        xb0 = __expf(fminf(e0, 60.f));
        xb1 = __expf(fminf(e1, 60.f));
        xb2 = __expf(fminf(e2, 60.f));
        xb3 = __expf(fminf(e3, 60.f));
      }
      float sa0 = xa0, sa1 = xa1, sa2 = xa2, sa3 = xa3;
      float sb0 = xb0, sb1 = xb1, sb2 = xb2, sb3 = xb3;
#pragma unroll
      for (int o = 16; o; o >>= 1) {
        sa0 += __shfl_xor(sa0, o, 64);
        sa1 += __shfl_xor(sa1, o, 64);
        sa2 += __shfl_xor(sa2, o, 64);
        sa3 += __shfl_xor(sa3, o, 64);
        sb0 += __shfl_xor(sb0, o, 64);
        sb1 += __shfl_xor(sb1, o, 64);
        sb2 += __shfl_xor(sb2, o, 64);
        sb3 += __shfl_xor(sb3, o, 64);
      }
      unsigned w01a = pack_h2(xa0 / (sa0 + 1e-16f), xa1 / (sa1 + 1e-16f));
      unsigned w23a = pack_h2(xa2 / (sa2 + 1e-16f), xa3 / (sa3 + 1e-16f));
      unsigned w01b = pack_h2(xb0 / (sb0 + 1e-16f), xb1 / (sb1 + 1e-16f));
      unsigned w23b = pack_h2(xb2 / (sb2 + 1e-16f), xb3 / (sb3 + 1e-16f));

      uint4* EB = (uint4*)&Mt[wv * 1056];
      EB[half * 32 + l5] = make_uint4((unsigned)offa, w01a, w23a, 0u);
      EB[64 + half * 32 + l5] = make_uint4((unsigned)offb, w01b, w23b, 0u);

      int g = l5 >> 4, li = l5 & 15;
      const uint2* h4p = (const uint2*)h;
      __half2 z = __floats2half2_rn(0.f, 0.f);
      __half2 pa0 = z, pa1 = z, pa2 = z, pa3 = z, pa4 = z, pa5 = z, pa6 = z, pa7 = z;
      __half2 pb0 = z, pb1 = z, pb2 = z, pb3 = z, pb4 = z, pb5 = z, pb6 = z, pb7 = z;
      int mm = max(max(dA0, dB0), max(dA1, dB1));
      int ebase = half * 32;
#pragma unroll 2
      for (int j = 0; j < mm; j += 2) {
        uint4 ra = EB[ebase + j + g];
        uint4 rb = EB[64 + ebase + j + g];
        uint2 hva = h4p[((int)ra.x >> 2) + li];
        uint2 hvb = h4p[((int)rb.x >> 2) + li];
        {
          __half2 ha = uas_h2(hva.x), hb = uas_h2(hva.y);
          __half2 wA = uas_h2(ra.y), wB = uas_h2(ra.z);
          __half2 c0 = __low2half2(ha), c1 = __high2half2(ha);
          __half2 c2 = __low2half2(hb), c3 = __high2half2(hb);
          pa0 = __hfma2(c0, wA, pa0); pa1 = __hfma2(c0, wB, pa1);
          pa2 = __hfma2(c1, wA, pa2); pa3 = __hfma2(c1, wB, pa3);
          pa4 = __hfma2(c2, wA, pa4); pa5 = __hfma2(c2, wB, pa5);
          pa6 = __hfma2(c3, wA, pa6); pa7 = __hfma2(c3, wB, pa7);
        }
        {
          __half2 ha = uas_h2(hvb.x), hb = uas_h2(hvb.y);
          __half2 wA = uas_h2(rb.y), wB = uas_h2(rb.z);
          __half2 c0 = __low2half2(ha), c1 = __high2half2(ha);
          __half2 c2 = __low2half2(hb), c3 = __high2half2(hb);
          pb0 = __hfma2(c0, wA, pb0); pb1 = __hfma2(c0, wB, pb1);
          pb2 = __hfma2(c1, wA, pb2); pb3 = __hfma2(c1, wB, pb3);
          pb4 = __hfma2(c2, wA, pb4); pb5 = __hfma2(c2, wB, pb5);
          pb6 = __hfma2(c3, wA, pb6); pb7 = __hfma2(c3, wB, pb7);
        }
      }
      pa0 = xor16_add(pa0); pa1 = xor16_add(pa1); pa2 = xor16_add(pa2); pa3 = xor16_add(pa3);
      pa4 = xor16_add(pa4); pa5 = xor16_add(pa5); pa6 = xor16_add(pa6); pa7 = xor16_add(pa7);
      pb0 = xor16_add(pb0); pb1 = xor16_add(pb1); pb2 = xor16_add(pb2); pb3 = xor16_add(pb3);
      pb4 = xor16_add(pb4); pb5 = xor16_add(pb5); pb6 = xor16_add(pb6); pb7 = xor16_add(pb7);
      if (g == 0) {
        __half* rowA = &Mt[(slotA & 15) * 264 + li * 16];
        __half* rowB = &Mt[(slotB & 15) * 264 + li * 16];
        uint4 s1, s2;
        s1.x = h2_as_u(pa0); s1.y = h2_as_u(pa1); s1.z = h2_as_u(pa2); s1.w = h2_as_u(pa3);
        s2.x = h2_as_u(pa4); s2.y = h2_as_u(pa5); s2.z = h2_as_u(pa6); s2.w = h2_as_u(pa7);
        *(uint4*)&rowA[0] = s1;
        *(uint4*)&rowA[8] = s2;
        s1.x = h2_as_u(pb0); s1.y = h2_as_u(pb1); s1.z = h2_as_u(pb2); s1.w = h2_as_u(pb3);
        s2.x = h2_as_u(pb4); s2.y = h2_as_u(pb5); s2.z = h2_as_u(pb6); s2.w = h2_as_u(pb7);
        *(uint4*)&rowB[0] = s1;
        *(uint4*)&rowB[8] = s2;
      }
    } else {
      gat_pair(pr0, lane, half, l5, N, perm, h, as_, ad_, rowptr, col, Mt);
      gat_pair(pr1, lane, half, l5, N, perm, h, as_, ad_, rowptr, col, Mt);
    }
  } else if (has0) {
    gat_pair(pr0, lane, half, l5, N, perm, h, as_, ad_, rowptr, col, Mt);
  }
  __syncthreads();

  // ---- phase 2: head-mean GEMM (+ next-layer attn scalars) from LDS tile ----
  int quad = lane >> 4, n16 = lane & 15;
  const f16x8* WC = (const f16x8*)Wcat;
  int ch1 = wv * 16 + n16;
  float bias1 = bg[ch1];
  f32x4 c1 = {0.f, 0.f, 0.f, 0.f};
#pragma unroll
  for (int i = 0; i < 8; ++i) {
    f16x8 a = *(const f16x8*)&Mt[n16 * 264 + (i * 4 + quad) * 8];
    c1 = __builtin_amdgcn_mfma_f32_16x16x32_f16(a, WC[ch1 * 32 + i * 4 + quad], c1, 0, 0, 0);
  }
#pragma unroll
  for (int r = 0; r < 4; ++r) {
    float v = fmaxf(c1[r] + bias1, 0.f);
    O[(quad * 4 + r) * 72 + ch1] = __float2half(v);
  }
  __syncthreads();
  {
    int nd = tid >> 4, c0 = (tid & 15) * 4;
    int slot = tile * 16 + nd;
    if (slot < N) {
      int node = perm[slot];
      uint2 v = *(const uint2*)&O[nd * 72 + c0];
      *(uint2*)&hout[(size_t)node * 64 + c0] = v;
    }
  }
  if (!FIN) {
    const f16x8* WN = (const f16x8*)Wn;
    f16x8 a0 = *(const f16x8*)&O[n16 * 72 + quad * 8];
    f16x8 a1 = *(const f16x8*)&O[n16 * 72 + 32 + quad * 8];
    f32x4 accs[4];
#pragma unroll
    for (int nt = 0; nt < 4; ++nt) {
      int ch = wv * 64 + nt * 16 + n16;
      f32x4 zz = {0.f, 0.f, 0.f, 0.f};
      zz = __builtin_amdgcn_mfma_f32_16x16x32_f16(a0, WN[ch * 8 + quad], zz, 0, 0, 0);
      zz = __builtin_amdgcn_mfma_f32_16x16x32_f16(a1, WN[ch * 8 + 4 + quad], zz, 0, 0, 0);
      accs[nt] = zz;
    }
#pragma unroll
    for (int r = 0; r < 4; ++r) {
      float vs = 0.f, vd = 0.f;
#pragma unroll
      for (int nt = 0; nt < 4; ++nt) {
        int ch = wv * 64 + nt * 16 + n16;
        vs = fmaf(accs[nt][r], asrc[ch], vs);
        vd = fmaf(accs[nt][r], adst[ch], vd);
      }
#pragma unroll
      for (int o = 8; o; o >>= 1) {
        vs += __shfl_xor(vs, o, 64);
        vd += __shfl_xor(vd, o, 64);
      }
      int slot = tile * 16 + quad * 4 + r;
      if (n16 == 0 && slot < N) {
        int node = perm[slot];
        nas[(size_t)node * 4 + wv] = vs;
        nad[(size_t)node * 4 + wv] = vd;
      }
    }
  }
}

// ---------------- graph mean pool ----------------
__global__ __launch_bounds__(256) void k_pool(
    const __half* __restrict__ hh, const int* __restrict__ batch,
    float* __restrict__ sums, float* __restrict__ cnt, int N) {
  int c = threadIdx.x & 63, r = threadIdx.x >> 6;
  int base = blockIdx.x * 64 + r * 16;
  float acc = 0.f;
  int curg = -1, cacc = 0;
  for (int i = 0; i < 16; ++i) {
    int n = base + i;
    if (n >= N) break;
    int g = batch[n];
    if (g != curg) {
      if (curg >= 0) {
        atomicAdd(&sums[curg * HID + c], acc);
        if (c == 0) atomicAdd(&cnt[curg], (float)cacc);
      }
      curg = g; acc = 0.f; cacc = 0;
    }
    acc += __half2float(hh[(size_t)n * HID + c]);
    cacc++;
  }
  if (curg >= 0) {
    atomicAdd(&sums[curg * HID + c], acc);
    if (c == 0) atomicAdd(&cnt[curg], (float)cacc);
  }
}

// ---------------- readout ----------------
__global__ void k_out(const float* __restrict__ sums, const float* __restrict__ cnt,
                      const float* __restrict__ Wout, const float* __restrict__ bout,
                      float* __restrict__ out) {
  int g = blockIdx.x, lane = threadIdx.x;
  float cg = fmaxf(cnt[g], 1.f);
  float v = (sums[g * HID + lane] / cg) * Wout[lane];
#pragma unroll
  for (int o = 32; o; o >>= 1) v += __shfl_xor(v, o, 64);
  if (lane == 0) out[g] = 1.f / (1.f + __expf(-v));
}

extern "C" void kernel_launch(void* const* d_in, const int* in_sizes, int n_in,
                              void* d_out, int out_size, void* d_ws, size_t ws_size,
                              hipStream_t stream) {
  const float* x    = (const float*)d_in[0];
  const int*   ei   = (const int*)d_in[1];
  const int*   batch= (const int*)d_in[2];
  const float* Win  = (const float*)d_in[3];
  const float* bin  = (const float*)d_in[4];
  const float* Wout = (const float*)d_in[5];
  const float* bout = (const float*)d_in[6];
  const float* Wl[3]    = {(const float*)d_in[7],  (const float*)d_in[11], (const float*)d_in[15]};
  const float* asrcl[3] = {(const float*)d_in[8],  (const float*)d_in[12], (const float*)d_in[16]};
  const float* adstl[3] = {(const float*)d_in[9],  (const float*)d_in[13], (const float*)d_in[17]};
  const float* bgl[3]   = {(const float*)d_in[10], (const float*)d_in[14], (const float*)d_in[18]};

  int N = in_sizes[2];       // 50000
  int E = in_sizes[1] / 2;   // 800000
  int EE = E + N;

  char* p = (char*)d_ws;
  auto alloc = [&](size_t bytes) {
    char* r = p;
    p += (bytes + 255) & ~(size_t)255;
    return r;
  };
  int*      rowptr = (int*)alloc((size_t)(N + 1) * 4);
  int*      col    = (int*)alloc((size_t)EE * 4);
  unsigned* tmp    = (unsigned*)alloc((size_t)NBUCK * BSLOT * 4);
  int*      bcur   = (int*)alloc(NBUCK * 4);
  int*      ghist  = (int*)alloc(256 * 4);
  int*      dcur   = (int*)alloc(256 * 4);
  int*      perm   = (int*)alloc((size_t)N * 4);
  float*    vb     = (float*)alloc(128 * 4);
  float*    c8     = (float*)alloc(8 * 4);
  __half*   hhA    = (__half*)alloc((size_t)N * HID * 2);
  __half*   hhB    = (__half*)alloc((size_t)N * HID * 2);
  float*    asA    = (float*)alloc((size_t)N * HEADS * 4);
  float*    adA    = (float*)alloc((size_t)N * HEADS * 4);
  float*    asB    = (float*)alloc((size_t)N * HEADS * 4);
  float*    adB    = (float*)alloc((size_t)N * HEADS * 4);
  __half*   Wh3    = (__half*)alloc(3 * 16384 * 2);
  __half*   Wcat3  = (__half*)alloc(3 * 16384 * 2);
  float*    sums   = (float*)alloc((size_t)(GCNT * HID + GCNT) * 4);
  float*    cnt    = sums + GCNT * HID;

  int tiles = (N + 15) / 16;

  k_pre<<<2, 256, 0, stream>>>(Wl[0], asrcl[0], adstl[0], Win, bin, bcur, ghist, vb, c8);
  k_bucket<<<(EE + SCHUNK - 1) / SCHUNK, 256, 0, stream>>>(ei, bcur, tmp, E, N);
  k_bsort<<<NBUCK, 256, 0, stream>>>(tmp, bcur, rowptr, col, ghist, N);
  k_dscan<<<1, 256, 0, stream>>>(ghist, dcur);
  k_dperm<<<(N + 255) / 256, 256, 0, stream>>>(rowptr, dcur, perm, N);

  k_init<<<401 + (N * HID + 255) / 256, 256, 0, stream>>>(
      x, Win, bin, Wl[0], Wl[1], Wl[2], Wh3, Wcat3, sums, vb, c8, asA, adA, hhA, N);

  k_gatf<false><<<tiles, 256, 0, stream>>>(hhA, asA, adA, rowptr, col, perm,
                                           Wcat3, bgl[0], Wh3 + 16384, asrcl[1], adstl[1],
                                           hhB, asB, adB, N);
  k_gatf<false><<<tiles, 256, 0, stream>>>(hhB, asB, adB, rowptr, col, perm,
                                           Wcat3 + 16384, bgl[1], Wh3 + 32768, asrcl[2], adstl[2],
                                           hhA, asA, adA, N);
  k_gatf<true><<<tiles, 256, 0, stream>>>(hhA, asA, adA, rowptr, col, perm,
                                          Wcat3 + 32768, bgl[2], nullptr, nullptr, nullptr,
                                          hhB, nullptr, nullptr, N);

  k_pool<<<(N + 63) / 64, 256, 0, stream>>>(hhB, batch, sums, cnt, N);
  k_out<<<GCNT, 64, 0, stream>>>(sums, cnt, Wout, bout, (float*)d_out);
}